// Round 6
// baseline (4073.241 us; speedup 1.0000x reference)
//
#include <hip/hip_runtime.h>
#include <hip/hip_bf16.h>

// CirculantElmanCell: T=1024, B=16, D=2048
// out0: output [T,B,D] f32 ; out1: h [T+1,B,D] f32 (concatenated in d_out)

typedef __attribute__((ext_vector_type(8))) unsigned short us8;
typedef __attribute__((ext_vector_type(8))) __bf16 bf16x8;
typedef __attribute__((ext_vector_type(4))) float f32x4;

__device__ __forceinline__ int SIGF(int a){ return a ^ (((a >> 8) & 3) << 2) ^ ((a >> 6) & 3); }
__device__ __forceinline__ int rev2i(int v){ return ((v & 1) << 1) | ((v >> 1) & 1); }
__device__ __forceinline__ int PERMF(int i){
  return rev2i((i >> 8) & 3) | (rev2i((i >> 6) & 3) << 2) | (rev2i((i >> 4) & 3) << 4)
       | (rev2i((i >> 2) & 3) << 6) | (rev2i(i & 3) << 8);
}

// LDS-only barrier: no vmcnt drain (global loads/stores stay in flight)
#define LDSBAR() do { \
  asm volatile("s_waitcnt lgkmcnt(0)\n\ts_barrier" ::: "memory"); \
  __builtin_amdgcn_sched_barrier(0); \
} while (0)

__device__ __forceinline__ unsigned short f2bf(float f){
  unsigned int u = __float_as_uint(f);
  return (unsigned short)((u + 0x7FFFu + ((u >> 16) & 1u)) >> 16);
}

__device__ __forceinline__ void sincos2pi(float fr, float& sn, float& co){
#if __has_builtin(__builtin_amdgcn_sinf) && __has_builtin(__builtin_amdgcn_cosf)
  sn = __builtin_amdgcn_sinf(fr);   // v_sin_f32: revolutions
  co = __builtin_amdgcn_cosf(fr);
#else
  __sincosf(fr * 6.28318530717958647692f, &sn, &co);
#endif
}

__device__ __forceinline__ float2 cmul(float2 a, float2 b){
  return make_float2(a.x*b.x - a.y*b.y, a.x*b.y + a.y*b.x);
}
__device__ __forceinline__ float2 cmulc(float2 a, float2 b){   // a * conj(b)
  return make_float2(a.x*b.x + a.y*b.y, a.y*b.x - a.x*b.y);
}
__device__ __forceinline__ float2 cadd(float2 a, float2 b){ return make_float2(a.x+b.x, a.y+b.y); }
__device__ __forceinline__ float2 csub(float2 a, float2 b){ return make_float2(a.x-b.x, a.y-b.y); }

__device__ __forceinline__ float tanh_fast(float x){
  float e = __expf(2.0f * x);
  return 1.0f - 2.0f / (e + 1.0f);
}

__device__ __forceinline__ float2 wn(int num, float dinv, int sgn){
  float sn, co; sincos2pi((float)num * dinv, sn, co);
  return make_float2(co, sgn > 0 ? sn : -sn);
}

// ---------------- cross-lane exchange primitives ----------------
template<int CTRL>
__device__ __forceinline__ float2 dpp2(float2 v){
  float2 r;
  r.x = __int_as_float(__builtin_amdgcn_mov_dpp(__float_as_int(v.x), CTRL, 0xF, 0xF, true));
  r.y = __int_as_float(__builtin_amdgcn_mov_dpp(__float_as_int(v.y), CTRL, 0xF, 0xF, true));
  return r;
}
template<int IMM>
__device__ __forceinline__ float2 swz2(float2 v){
  float2 r;
  r.x = __int_as_float(__builtin_amdgcn_ds_swizzle(__float_as_int(v.x), IMM));
  r.y = __int_as_float(__builtin_amdgcn_ds_swizzle(__float_as_int(v.y), IMM));
  return r;
}
__device__ __forceinline__ float2 bperm2(int addr, float2 v){
  float2 r;
  r.x = __int_as_float(__builtin_amdgcn_ds_bpermute(addr, __float_as_int(v.x)));
  r.y = __int_as_float(__builtin_amdgcn_ds_bpermute(addr, __float_as_int(v.y)));
  return r;
}
#define DPP_XOR1 0xB1  // quad_perm [1,0,3,2]
#define DPP_XOR2 0x4E  // quad_perm [2,3,0,1]

// ---------------- radix-4 building blocks (verbatim from verified R5) ----------------
template<int POS>  // POS=0: fwd, POS=1: inv (twiddle conjugated)
__device__ __forceinline__ float2 lds4(const float2* buf, int a0, int a1, int a2, int a3,
                                       float sB, float sD, bool sel, float2 tw){
  float2 in0 = buf[a0], in1 = buf[a1], in2 = buf[a2], in3 = buf[a3];
  float2 u = make_float2(fmaf(sB, in2.x, in0.x), fmaf(sB, in2.y, in0.y));
  float2 v = make_float2(fmaf(sB, in3.x, in1.x), fmaf(sB, in3.y, in1.y));
  float2 iv = POS ? make_float2(-v.y, v.x) : make_float2(v.y, -v.x);
  float2 se = sel ? iv : v;
  float2 X = make_float2(fmaf(sD, se.x, u.x), fmaf(sD, se.y, u.y));
  return POS ? cmulc(X, tw) : cmul(X, tw);
}

template<int POS>
__device__ __forceinline__ float2 round2f(float2 own, float2 par, bool c0, bool c1, float sgn0){
  float2 vk = c0 ? par : own;
  float2 vr = c0 ? own : par;
  float2 vrr = POS ? make_float2(-vr.y, vr.x) : make_float2(vr.y, -vr.x);
  float2 rot = c1 ? vrr : vr;
  return make_float2(fmaf(sgn0, rot.x, vk.x), fmaf(sgn0, rot.y, vk.y));
}

template<int POS>
__device__ __forceinline__ float2 lanes3(float2 T, int bpa,
    float sH2, bool c02, bool c12, float sL2, float2 tw2,
    float sH3, bool c03, bool c13, float sL3, float2 tw3,
    float sH4, bool c04, bool c14, float sL4){
  { // d=16: lane^32 (bpermute), lane^16 (swizzle)
    float2 par = bperm2(bpa, T);
    T.x = fmaf(sH2, T.x, par.x); T.y = fmaf(sH2, T.y, par.y);
    float2 p2 = swz2<0x401F>(T);
    T = round2f<POS>(T, p2, c02, c12, sL2);
    T = POS ? cmulc(T, tw2) : cmul(T, tw2);
  }
  { // d=4: lane^8, lane^4
    float2 par = swz2<0x201F>(T);
    T.x = fmaf(sH3, T.x, par.x); T.y = fmaf(sH3, T.y, par.y);
    float2 p2 = swz2<0x101F>(T);
    T = round2f<POS>(T, p2, c03, c13, sL3);
    T = POS ? cmulc(T, tw3) : cmul(T, tw3);
  }
  { // d=1: lane^2, lane^1
    float2 par = dpp2<DPP_XOR2>(T);
    T.x = fmaf(sH4, T.x, par.x); T.y = fmaf(sH4, T.y, par.y);
    float2 p2 = dpp2<DPP_XOR1>(T);
    T = round2f<POS>(T, p2, c04, c14, sL4);
  }
  return T;
}

// ---------------- per-thread constants ----------------
struct QC {
  float2 tw0, tw1, tw2, tw3, P, Q;
  float sB0, sD0, sB1, sD1;
  float sH2, sL2, sH3, sL3, sH4, sL4;
  bool sel0, sel1, c02, c12, c03, c13, c04, c14;
  int sfi, swP, smir, bpa;
  int aA0, aA1, aA2, aA3, aB0, aB1, aB2, aB3;
};

__device__ __forceinline__ void make_qc(int i, const float2* __restrict__ lam_g, QC& S){
  const int p0 = rev2i((i >> 8) & 3);
  const int p1 = rev2i((i >> 6) & 3);
  const int p2v = rev2i((i >> 4) & 3);
  const int p3v = rev2i((i >> 2) & 3);
  S.tw0 = wn(((i & 255) * p0) & 1023, 1.0f/1024.0f, -1);
  S.tw1 = wn(((i & 63) * p1) & 255, 1.0f/256.0f, -1);
  S.tw2 = wn(((i & 15) * p2v) & 63, 1.0f/64.0f, -1);
  S.tw3 = wn(((i & 3) * p3v) & 15, 1.0f/16.0f, -1);
  // mid-stage fold: out = P*zk + Q*conj(zp)   (algebraic collapse of Hermitian chain)
  float2 w = wn(i & 2047, 1.0f/2048.0f, -1);
  float2 lamA = lam_g[i], lamB = lam_g[i + 1024];
  float2 al = make_float2(0.5f*(1.0f + w.y), -0.5f*w.x);   // (1 - i w)/2
  float2 be = make_float2(0.5f*(1.0f - w.y),  0.5f*w.x);   // (1 + i w)/2
  float2 ga = make_float2(1.0f + w.y,  w.x);               // 1 + i conj(w)
  float2 de = make_float2(1.0f - w.y, -w.x);               // 1 - i conj(w)
  float2 gA = cmul(ga, lamA), dB = cmul(de, lamB);
  S.P = cadd(cmul(gA, al), cmul(dB, be));
  S.Q = cadd(cmul(gA, be), cmul(dB, al));
  S.sB0 = (p0 & 1) ? -1.f : 1.f; S.sD0 = (p0 & 2) ? -1.f : 1.f; S.sel0 = p0 & 1;
  S.sB1 = (p1 & 1) ? -1.f : 1.f; S.sD1 = (p1 & 2) ? -1.f : 1.f; S.sel1 = p1 & 1;
  S.c02 = (i >> 4) & 1; S.c12 = (i >> 5) & 1;
  S.c03 = (i >> 2) & 1; S.c13 = (i >> 3) & 1;
  S.c04 = i & 1;        S.c14 = (i >> 1) & 1;
  S.sH2 = S.c12 ? -1.f : 1.f; S.sL2 = S.c02 ? -1.f : 1.f;
  S.sH3 = S.c13 ? -1.f : 1.f; S.sL3 = S.c03 ? -1.f : 1.f;
  S.sH4 = S.c14 ? -1.f : 1.f; S.sL4 = S.c04 ? -1.f : 1.f;
  S.sfi = SIGF(i); S.swP = SIGF(PERMF(i)); S.smir = SIGF((1024 - i) & 1023);
  S.bpa = ((i & 63) ^ 32) << 2;
  const int r256 = i & 255;
  S.aA0 = SIGF(r256); S.aA1 = SIGF(r256 + 256); S.aA2 = SIGF(r256 + 512); S.aA3 = SIGF(r256 + 768);
  const int b64 = (i & ~255) + (i & 63);
  S.aB0 = SIGF(b64); S.aB1 = SIGF(b64 + 64); S.aB2 = SIGF(b64 + 128); S.aB3 = SIGF(b64 + 192);
}

// full conv body: fwd FFT, spectral multiply, inv FFT; result at bA[S.sfi]
__device__ __forceinline__ void fftconv(float2* hz, float2* bA, float2* bB, const QC& S){
  float2 T = lds4<0>(hz, S.aA0, S.aA1, S.aA2, S.aA3, S.sB0, S.sD0, S.sel0, S.tw0);
  bA[S.sfi] = T; LDSBAR();
  T = lds4<0>(bA, S.aB0, S.aB1, S.aB2, S.aB3, S.sB1, S.sD1, S.sel1, S.tw1);
  T = lanes3<0>(T, S.bpa, S.sH2, S.c02, S.c12, S.sL2, S.tw2,
                S.sH3, S.c03, S.c13, S.sL3, S.tw3, S.sH4, S.c04, S.c14, S.sL4);
  bB[S.swP] = T; LDSBAR();
  {
    float2 zk = bB[S.sfi], zp = bB[S.smir];
    bA[S.sfi] = cadd(cmul(S.P, zk), cmulc(S.Q, zp));
  }
  LDSBAR();
  T = lds4<1>(bA, S.aA0, S.aA1, S.aA2, S.aA3, S.sB0, S.sD0, S.sel0, S.tw0);
  bB[S.sfi] = T; LDSBAR();
  T = lds4<1>(bB, S.aB0, S.aB1, S.aB2, S.aB3, S.sB1, S.sD1, S.sel1, S.tw1);
  T = lanes3<1>(T, S.bpa, S.sH2, S.c02, S.c12, S.sL2, S.tw2,
                S.sH3, S.c03, S.c13, S.sL3, S.tw3, S.sH4, S.c04, S.c14, S.sL4);
  bA[S.swP] = T; LDSBAR();
}

// ---------------- f32 -> bf16 bulk convert ----------------
__global__ __launch_bounds__(256) void cvt_bf16(const float* __restrict__ in,
                                                unsigned short* __restrict__ out, int n8){
  int i = blockIdx.x * 256 + threadIdx.x;
  if (i >= n8) return;
  float4 a = ((const float4*)in)[2 * i];
  float4 b = ((const float4*)in)[2 * i + 1];
  us8 r;
  r[0] = f2bf(a.x); r[1] = f2bf(a.y); r[2] = f2bf(a.z); r[3] = f2bf(a.w);
  r[4] = f2bf(b.x); r[5] = f2bf(b.y); r[6] = f2bf(b.z); r[7] = f2bf(b.w);
  ((us8*)out)[i] = r;
}

// ---------------- lam[k] = fft(c)[k] / 2048 ----------------
__global__ __launch_bounds__(256) void dft_c(const float* __restrict__ c, float2* __restrict__ lam){
  __shared__ float cs[2048];
  int tid = threadIdx.x;
  for (int i = tid; i < 2048; i += 256) cs[i] = c[i];
  __syncthreads();
  int k = blockIdx.x * 256 + tid;
  float sr = 0.f, si = 0.f;
  for (int j = 0; j < 2048; ++j){
    int ph = (j * k) & 2047;
    float sn, co; sincos2pi((float)ph * (1.0f / 2048.0f), sn, co);
    float cv = cs[j];
    sr = __fmaf_rn(cv,  co, sr);
    si = __fmaf_rn(-cv, sn, si);
  }
  lam[k] = make_float2(sr * (1.0f / 2048.0f), si * (1.0f / 2048.0f));
}

// =====================================================================
// mega: blocks [0,16) recur ; [16,144) circx producers ; [144,1168) gemm
// flags: gcnt[128] (target 32), wcnt[128] (target 128); chunk x covers t in [8x,8x+8)
// =====================================================================
__global__ __launch_bounds__(1024, 4) void mega(
    const float* __restrict__ x, const unsigned short* __restrict__ xb,
    const unsigned short* __restrict__ Wb, const float* __restrict__ h0,
    const float2* __restrict__ lamh, const float2* __restrict__ lamx,
    const float* __restrict__ bias, const float* __restrict__ bg,
    float* __restrict__ outp, float* __restrict__ houtp, int* __restrict__ flags){
  __shared__ __align__(16) char smem[49152];
  const int bid = blockIdx.x;
  const int tid = threadIdx.x;
  int* gcnt = flags;
  int* wcnt = flags + 128;

  if (bid < 16){
    // ---------------- recur consumer ----------------
    float2* hz = (float2*)smem; float2* bA = hz + 1024; float2* bB = hz + 2048;
    const int i = tid, b = bid;
    QC S; make_qc(i, lamh, S);
    {
      const float2* h02 = (const float2*)(h0 + (size_t)b * 2048);
      float2* hrow0 = (float2*)(houtp + (size_t)b * 2048);
      float2 v = h02[i]; hz[S.sfi] = v; hrow0[i] = v;
    }
    __syncthreads();
    #pragma unroll 1
    for (int t = 0; t < 1024; ++t){
      if ((t & 7) == 0){
        if (tid == 0){
          const int xk = t >> 3;
          while (__hip_atomic_load(&gcnt[xk], __ATOMIC_RELAXED, __HIP_MEMORY_SCOPE_AGENT) < 32)
            __builtin_amdgcn_s_sleep(32);
          while (__hip_atomic_load(&wcnt[xk], __ATOMIC_RELAXED, __HIP_MEMORY_SCOPE_AGENT) < 128)
            __builtin_amdgcn_s_sleep(32);
        }
        __syncthreads();
        __threadfence();   // acquire: make producer writes visible to this block
      }
      float* orow = outp  + ((size_t)t * 16 + b) * 2048;
      float* hrow = houtp + ((size_t)(t + 1) * 16 + b) * 2048;
      float2 pr = *(const float2*)(orow + 2 * i);   // pre (circ_x + b)
      float2 gv = *(const float2*)(hrow + 2 * i);   // gate (silu)
      fftconv(hz, bA, bB, S);
      float2 y = bA[S.sfi];
      float hx = tanh_fast(y.x + pr.x);
      float hy = tanh_fast(y.y + pr.y);
      float ox = hx * gv.x, oy = hy * gv.y;
      asm volatile("" : "+v"(hx), "+v"(hy) : "v"(gv.x), "v"(gv.y));
      float2 hv = make_float2(hx, hy);
      hz[S.sfi] = hv;
      *(float2*)(hrow + 2 * i) = hv;
      *(float2*)(orow + 2 * i) = make_float2(ox, oy);
      LDSBAR();
    }
  } else if (bid < 144){
    // ---------------- circx producer: rows cblk + 128*k ----------------
    float2* hz = (float2*)smem; float2* bA = hz + 1024; float2* bB = hz + 2048;
    const int i = tid, cblk = bid - 16;
    QC S; make_qc(i, lamx, S);
    const float2 bv = ((const float2*)bias)[i];
    #pragma unroll 1
    for (int k = 0; k < 128; ++k){
      const size_t row = (size_t)cblk + ((size_t)k << 7);
      hz[S.sfi] = ((const float2*)(x + row * 2048))[i];
      LDSBAR();
      fftconv(hz, bA, bB, S);
      float2 y = bA[S.sfi];
      ((float2*)(outp + row * 2048))[i] = cadd(y, bv);
      __syncthreads();   // drains each wave's stores before flag release
      if (tid == 0){
        __threadfence();
        __hip_atomic_fetch_add(&wcnt[k], 1, __ATOMIC_RELEASE, __HIP_MEMORY_SCOPE_AGENT);
      }
    }
  } else {
    // ---------------- gemm producer: 4 independent 128x64 tiles ----------------
    const int q = bid - 144;
    const int g = tid >> 8, tid8 = tid & 255;
    const int tau = q * 4 + g;
    const int m0 = (tau >> 5) * 128, n0 = (tau & 31) * 64;
    unsigned short* As = (unsigned short*)(smem + g * 12288);   // 128x32
    unsigned short* Bs = As + 4096;                             // 64x32
    const int lane = tid8 & 63, wave = tid8 >> 6;
    const int srA = tid8 >> 1, scA = (tid8 & 1) << 4;
    const int srB = tid8 >> 2, scB = (tid8 & 3) << 3;
    const unsigned short* ga = xb + (size_t)(m0 + srA) * 2048 + scA;
    const unsigned short* gb = Wb + (size_t)(n0 + srB) * 2048 + scB;
    unsigned short* la = As + srA * 32 + scA;
    unsigned short* lb = Bs + srB * 32 + scB;
    f32x4 acc[2][4];
    #pragma unroll
    for (int m = 0; m < 2; ++m)
      #pragma unroll
      for (int n = 0; n < 4; ++n)
        acc[m][n] = f32x4{0.f, 0.f, 0.f, 0.f};
    const int arow = wave * 32 + (lane & 15);
    const int brow = lane & 15;
    const int koff = (lane >> 4) * 8;
    for (int ks = 0; ks < 64; ++ks){
      const int k0 = ks * 32;
      us8 va0 = *(const us8*)(ga + k0);
      us8 va1 = *(const us8*)(ga + k0 + 8);
      us8 vb0 = *(const us8*)(gb + k0);
      __syncthreads();
      *(us8*)(la)     = va0; *(us8*)(la + 8) = va1;
      *(us8*)(lb)     = vb0;
      __syncthreads();
      bf16x8 av[2], bvv[4];
      #pragma unroll
      for (int m = 0; m < 2; ++m) av[m] = *(const bf16x8*)(As + (arow + m * 16) * 32 + koff);
      #pragma unroll
      for (int n = 0; n < 4; ++n) bvv[n] = *(const bf16x8*)(Bs + (brow + n * 16) * 32 + koff);
      #pragma unroll
      for (int m = 0; m < 2; ++m)
        #pragma unroll
        for (int n = 0; n < 4; ++n)
          acc[m][n] = __builtin_amdgcn_mfma_f32_16x16x32_bf16(av[m], bvv[n], acc[m][n], 0, 0, 0);
    }
    #pragma unroll
    for (int n = 0; n < 4; ++n){
      const int ng = n0 + n * 16 + (lane & 15);
      const float bgv = bg[ng];
      #pragma unroll
      for (int m = 0; m < 2; ++m){
        const int mbase = m0 + wave * 32 + m * 16 + (lane >> 4) * 4;
        #pragma unroll
        for (int r = 0; r < 4; ++r){
          float v = acc[m][n][r] + bgv;
          float s = v / (1.0f + __expf(-v));
          houtp[(size_t)(mbase + r + 16) * 2048 + ng] = s;   // gate row m -> h row m+16
        }
      }
    }
    __syncthreads();
    if (tid == 0){
      __threadfence();
      __hip_atomic_fetch_add(&gcnt[q >> 3], 4, __ATOMIC_RELEASE, __HIP_MEMORY_SCOPE_AGENT);
    }
  }
}

extern "C" void kernel_launch(void* const* d_in, const int* in_sizes, int n_in,
                              void* d_out, int out_size, void* d_ws, size_t ws_size,
                              hipStream_t stream){
  const float* x  = (const float*)d_in[0];
  const float* h0 = (const float*)d_in[1];
  const float* ch = (const float*)d_in[2];
  const float* cx = (const float*)d_in[3];
  const float* Wg = (const float*)d_in[4];
  const float* bb = (const float*)d_in[5];
  const float* bg = (const float*)d_in[6];
  float* outp  = (float*)d_out;                        // [T,B,D]
  float* houtp = outp + (size_t)1024 * 16 * 2048;      // [T+1,B,D]

  char* w = (char*)d_ws;
  unsigned short* xb = (unsigned short*)w; w += (size_t)16384 * 2048 * 2;
  unsigned short* Wb = (unsigned short*)w; w += (size_t)2048 * 2048 * 2;
  float2* lamh = (float2*)w; w += 2048 * sizeof(float2);
  float2* lamx = (float2*)w; w += 2048 * sizeof(float2);
  int* flags   = (int*)w;   w += 256 * sizeof(int);

  cvt_bf16 <<<dim3(16384), dim3(256), 0, stream>>>(x,  xb, 16384 * 2048 / 8);
  cvt_bf16 <<<dim3(2048),  dim3(256), 0, stream>>>(Wg, Wb,  2048 * 2048 / 8);
  dft_c    <<<dim3(8),     dim3(256), 0, stream>>>(ch, lamh);
  dft_c    <<<dim3(8),     dim3(256), 0, stream>>>(cx, lamx);
  hipMemsetAsync(flags, 0, 256 * sizeof(int), stream);
  mega     <<<dim3(1168),  dim3(1024), 0, stream>>>(x, xb, Wb, h0, lamh, lamx,
                                                    bb, bg, outp, houtp, flags);
}

// Round 7
// 4060.186 us; speedup vs baseline: 1.0032x; 1.0032x over previous
//
#include <hip/hip_runtime.h>
#include <hip/hip_bf16.h>

// CirculantElmanCell: T=1024, B=16, D=2048
// out0: output [T,B,D] f32 ; out1: h [T+1,B,D] f32 (concatenated in d_out)

typedef __attribute__((ext_vector_type(8))) unsigned short us8;
typedef __attribute__((ext_vector_type(8))) __bf16 bf16x8;
typedef __attribute__((ext_vector_type(4))) float f32x4;

__device__ __forceinline__ int SIGF(int a){ return a ^ (((a >> 8) & 3) << 2) ^ ((a >> 6) & 3); }
__device__ __forceinline__ int rev2i(int v){ return ((v & 1) << 1) | ((v >> 1) & 1); }
__device__ __forceinline__ int PERMF(int i){
  return rev2i((i >> 8) & 3) | (rev2i((i >> 6) & 3) << 2) | (rev2i((i >> 4) & 3) << 4)
       | (rev2i((i >> 2) & 3) << 6) | (rev2i(i & 3) << 8);
}

// LDS-only barrier: no vmcnt drain (global loads/stores stay in flight)
#define LDSBAR() do { \
  asm volatile("s_waitcnt lgkmcnt(0)\n\ts_barrier" ::: "memory"); \
  __builtin_amdgcn_sched_barrier(0); \
} while (0)

__device__ __forceinline__ unsigned short f2bf(float f){
  unsigned int u = __float_as_uint(f);
  return (unsigned short)((u + 0x7FFFu + ((u >> 16) & 1u)) >> 16);
}

__device__ __forceinline__ void sincos2pi(float fr, float& sn, float& co){
#if __has_builtin(__builtin_amdgcn_sinf) && __has_builtin(__builtin_amdgcn_cosf)
  sn = __builtin_amdgcn_sinf(fr);   // v_sin_f32: revolutions
  co = __builtin_amdgcn_cosf(fr);
#else
  __sincosf(fr * 6.28318530717958647692f, &sn, &co);
#endif
}

__device__ __forceinline__ float2 cmul(float2 a, float2 b){
  return make_float2(a.x*b.x - a.y*b.y, a.x*b.y + a.y*b.x);
}
__device__ __forceinline__ float2 cmulc(float2 a, float2 b){   // a * conj(b)
  return make_float2(a.x*b.x + a.y*b.y, a.y*b.x - a.x*b.y);
}
__device__ __forceinline__ float2 cadd(float2 a, float2 b){ return make_float2(a.x+b.x, a.y+b.y); }
__device__ __forceinline__ float2 csub(float2 a, float2 b){ return make_float2(a.x-b.x, a.y-b.y); }

__device__ __forceinline__ float tanh_fast(float x){
  float e = __expf(2.0f * x);
  return 1.0f - 2.0f / (e + 1.0f);
}

__device__ __forceinline__ float2 wn(int num, float dinv, int sgn){
  float sn, co; sincos2pi((float)num * dinv, sn, co);
  return make_float2(co, sgn > 0 ? sn : -sn);
}

// ---------------- cross-lane exchange primitives ----------------
template<int CTRL>
__device__ __forceinline__ float2 dpp2(float2 v){
  float2 r;
  r.x = __int_as_float(__builtin_amdgcn_mov_dpp(__float_as_int(v.x), CTRL, 0xF, 0xF, true));
  r.y = __int_as_float(__builtin_amdgcn_mov_dpp(__float_as_int(v.y), CTRL, 0xF, 0xF, true));
  return r;
}
template<int IMM>
__device__ __forceinline__ float2 swz2(float2 v){
  float2 r;
  r.x = __int_as_float(__builtin_amdgcn_ds_swizzle(__float_as_int(v.x), IMM));
  r.y = __int_as_float(__builtin_amdgcn_ds_swizzle(__float_as_int(v.y), IMM));
  return r;
}
__device__ __forceinline__ float2 bperm2(int addr, float2 v){
  float2 r;
  r.x = __int_as_float(__builtin_amdgcn_ds_bpermute(addr, __float_as_int(v.x)));
  r.y = __int_as_float(__builtin_amdgcn_ds_bpermute(addr, __float_as_int(v.y)));
  return r;
}
#define DPP_XOR1 0xB1  // quad_perm [1,0,3,2]
#define DPP_XOR2 0x4E  // quad_perm [2,3,0,1]

// ---------------- radix-4 building blocks (verbatim, verified R5/R6) ----------------
template<int POS>  // POS=0: fwd, POS=1: inv (twiddle conjugated)
__device__ __forceinline__ float2 lds4(const float2* buf, int a0, int a1, int a2, int a3,
                                       float sB, float sD, bool sel, float2 tw){
  float2 in0 = buf[a0], in1 = buf[a1], in2 = buf[a2], in3 = buf[a3];
  float2 u = make_float2(fmaf(sB, in2.x, in0.x), fmaf(sB, in2.y, in0.y));
  float2 v = make_float2(fmaf(sB, in3.x, in1.x), fmaf(sB, in3.y, in1.y));
  float2 iv = POS ? make_float2(-v.y, v.x) : make_float2(v.y, -v.x);
  float2 se = sel ? iv : v;
  float2 X = make_float2(fmaf(sD, se.x, u.x), fmaf(sD, se.y, u.y));
  return POS ? cmulc(X, tw) : cmul(X, tw);
}

template<int POS>
__device__ __forceinline__ float2 round2f(float2 own, float2 par, bool c0, bool c1, float sgn0){
  float2 vk = c0 ? par : own;
  float2 vr = c0 ? own : par;
  float2 vrr = POS ? make_float2(-vr.y, vr.x) : make_float2(vr.y, -vr.x);
  float2 rot = c1 ? vrr : vr;
  return make_float2(fmaf(sgn0, rot.x, vk.x), fmaf(sgn0, rot.y, vk.y));
}

template<int POS>
__device__ __forceinline__ float2 lanes3(float2 T, int bpa,
    float sH2, bool c02, bool c12, float sL2, float2 tw2,
    float sH3, bool c03, bool c13, float sL3, float2 tw3,
    float sH4, bool c04, bool c14, float sL4){
  { // d=16: lane^32 (bpermute), lane^16 (swizzle)
    float2 par = bperm2(bpa, T);
    T.x = fmaf(sH2, T.x, par.x); T.y = fmaf(sH2, T.y, par.y);
    float2 p2 = swz2<0x401F>(T);
    T = round2f<POS>(T, p2, c02, c12, sL2);
    T = POS ? cmulc(T, tw2) : cmul(T, tw2);
  }
  { // d=4: lane^8, lane^4
    float2 par = swz2<0x201F>(T);
    T.x = fmaf(sH3, T.x, par.x); T.y = fmaf(sH3, T.y, par.y);
    float2 p2 = swz2<0x101F>(T);
    T = round2f<POS>(T, p2, c03, c13, sL3);
    T = POS ? cmulc(T, tw3) : cmul(T, tw3);
  }
  { // d=1: lane^2, lane^1
    float2 par = dpp2<DPP_XOR2>(T);
    T.x = fmaf(sH4, T.x, par.x); T.y = fmaf(sH4, T.y, par.y);
    float2 p2 = dpp2<DPP_XOR1>(T);
    T = round2f<POS>(T, p2, c04, c14, sL4);
  }
  return T;
}

// ---------------- per-thread constants ----------------
struct QC {
  float2 tw0, tw1, tw2, tw3, P, Q;
  float sB0, sD0, sB1, sD1;
  float sH2, sL2, sH3, sL3, sH4, sL4;
  bool sel0, sel1, c02, c12, c03, c13, c04, c14;
  int sfi, swP, smir, bpa;
  int aA0, aA1, aA2, aA3, aB0, aB1, aB2, aB3;
};

__device__ __forceinline__ void make_qc(int i, const float2* __restrict__ lam_g, QC& S){
  const int p0 = rev2i((i >> 8) & 3);
  const int p1 = rev2i((i >> 6) & 3);
  const int p2v = rev2i((i >> 4) & 3);
  const int p3v = rev2i((i >> 2) & 3);
  S.tw0 = wn(((i & 255) * p0) & 1023, 1.0f/1024.0f, -1);
  S.tw1 = wn(((i & 63) * p1) & 255, 1.0f/256.0f, -1);
  S.tw2 = wn(((i & 15) * p2v) & 63, 1.0f/64.0f, -1);
  S.tw3 = wn(((i & 3) * p3v) & 15, 1.0f/16.0f, -1);
  // mid-stage fold: out = P*zk + Q*conj(zp)
  float2 w = wn(i & 2047, 1.0f/2048.0f, -1);
  float2 lamA = lam_g[i], lamB = lam_g[i + 1024];
  float2 al = make_float2(0.5f*(1.0f + w.y), -0.5f*w.x);   // (1 - i w)/2
  float2 be = make_float2(0.5f*(1.0f - w.y),  0.5f*w.x);   // (1 + i w)/2
  float2 ga = make_float2(1.0f + w.y,  w.x);               // 1 + i conj(w)
  float2 de = make_float2(1.0f - w.y, -w.x);               // 1 - i conj(w)
  float2 gA = cmul(ga, lamA), dB = cmul(de, lamB);
  S.P = cadd(cmul(gA, al), cmul(dB, be));
  S.Q = cadd(cmul(gA, be), cmul(dB, al));
  S.sB0 = (p0 & 1) ? -1.f : 1.f; S.sD0 = (p0 & 2) ? -1.f : 1.f; S.sel0 = p0 & 1;
  S.sB1 = (p1 & 1) ? -1.f : 1.f; S.sD1 = (p1 & 2) ? -1.f : 1.f; S.sel1 = p1 & 1;
  S.c02 = (i >> 4) & 1; S.c12 = (i >> 5) & 1;
  S.c03 = (i >> 2) & 1; S.c13 = (i >> 3) & 1;
  S.c04 = i & 1;        S.c14 = (i >> 1) & 1;
  S.sH2 = S.c12 ? -1.f : 1.f; S.sL2 = S.c02 ? -1.f : 1.f;
  S.sH3 = S.c13 ? -1.f : 1.f; S.sL3 = S.c03 ? -1.f : 1.f;
  S.sH4 = S.c14 ? -1.f : 1.f; S.sL4 = S.c04 ? -1.f : 1.f;
  S.sfi = SIGF(i); S.swP = SIGF(PERMF(i)); S.smir = SIGF((1024 - i) & 1023);
  S.bpa = ((i & 63) ^ 32) << 2;
  const int r256 = i & 255;
  S.aA0 = SIGF(r256); S.aA1 = SIGF(r256 + 256); S.aA2 = SIGF(r256 + 512); S.aA3 = SIGF(r256 + 768);
  const int b64 = (i & ~255) + (i & 63);
  S.aB0 = SIGF(b64); S.aB1 = SIGF(b64 + 64); S.aB2 = SIGF(b64 + 128); S.aB3 = SIGF(b64 + 192);
}

// full conv body: fwd FFT, spectral multiply, inv FFT; result at bA[S.sfi]
__device__ __forceinline__ void fftconv(float2* hz, float2* bA, float2* bB, const QC& S){
  float2 T = lds4<0>(hz, S.aA0, S.aA1, S.aA2, S.aA3, S.sB0, S.sD0, S.sel0, S.tw0);
  bA[S.sfi] = T; LDSBAR();
  T = lds4<0>(bA, S.aB0, S.aB1, S.aB2, S.aB3, S.sB1, S.sD1, S.sel1, S.tw1);
  T = lanes3<0>(T, S.bpa, S.sH2, S.c02, S.c12, S.sL2, S.tw2,
                S.sH3, S.c03, S.c13, S.sL3, S.tw3, S.sH4, S.c04, S.c14, S.sL4);
  bB[S.swP] = T; LDSBAR();
  {
    float2 zk = bB[S.sfi], zp = bB[S.smir];
    bA[S.sfi] = cadd(cmul(S.P, zk), cmulc(S.Q, zp));
  }
  LDSBAR();
  T = lds4<1>(bA, S.aA0, S.aA1, S.aA2, S.aA3, S.sB0, S.sD0, S.sel0, S.tw0);
  bB[S.sfi] = T; LDSBAR();
  T = lds4<1>(bB, S.aB0, S.aB1, S.aB2, S.aB3, S.sB1, S.sD1, S.sel1, S.tw1);
  T = lanes3<1>(T, S.bpa, S.sH2, S.c02, S.c12, S.sL2, S.tw2,
                S.sH3, S.c03, S.c13, S.sL3, S.tw3, S.sH4, S.c04, S.c14, S.sL4);
  bA[S.swP] = T; LDSBAR();
}

// ---------------- f32 -> bf16 bulk convert ----------------
__global__ __launch_bounds__(256) void cvt_bf16(const float* __restrict__ in,
                                                unsigned short* __restrict__ out, int n8){
  int i = blockIdx.x * 256 + threadIdx.x;
  if (i >= n8) return;
  float4 a = ((const float4*)in)[2 * i];
  float4 b = ((const float4*)in)[2 * i + 1];
  us8 r;
  r[0] = f2bf(a.x); r[1] = f2bf(a.y); r[2] = f2bf(a.z); r[3] = f2bf(a.w);
  r[4] = f2bf(b.x); r[5] = f2bf(b.y); r[6] = f2bf(b.z); r[7] = f2bf(b.w);
  ((us8*)out)[i] = r;
}

// ---------------- lam[k] = fft(c)[k] / 2048 ----------------
__global__ __launch_bounds__(256) void dft_c(const float* __restrict__ c, float2* __restrict__ lam){
  __shared__ float cs[2048];
  int tid = threadIdx.x;
  for (int i = tid; i < 2048; i += 256) cs[i] = c[i];
  __syncthreads();
  int k = blockIdx.x * 256 + tid;
  float sr = 0.f, si = 0.f;
  for (int j = 0; j < 2048; ++j){
    int ph = (j * k) & 2047;
    float sn, co; sincos2pi((float)ph * (1.0f / 2048.0f), sn, co);
    float cv = cs[j];
    sr = __fmaf_rn(cv,  co, sr);
    si = __fmaf_rn(-cv, sn, si);
  }
  lam[k] = make_float2(sr * (1.0f / 2048.0f), si * (1.0f / 2048.0f));
}

// =====================================================================
// mega v2: 96KB static LDS -> exactly 1 block/CU (CU isolation for recur).
// blocks [0,16) recur ; [16,144) circx producers ; [144,1168) gemm.
// flags: gcnt[128] (target 32), wcnt[128] (target 128); chunk x = t in [8x,8x+8)
// =====================================================================
__global__ __launch_bounds__(1024, 4) void mega(
    const float* __restrict__ x, const unsigned short* __restrict__ xb,
    const unsigned short* __restrict__ Wb, const float* __restrict__ h0,
    const float2* __restrict__ lamh, const float2* __restrict__ lamx,
    const float* __restrict__ bias, const float* __restrict__ bg,
    float* __restrict__ outp, float* __restrict__ houtp, int* __restrict__ flags){
  __shared__ __align__(16) char smem[98304];   // 96KB: forces 1 block/CU (2x96 > 160)
  const int bid = blockIdx.x;
  const int tid = threadIdx.x;
  int* gcnt = flags;
  int* wcnt = flags + 128;

  if (bid < 16){
    // ---------------- recur consumer (dedicated CU) ----------------
    float2* hz = (float2*)smem; float2* bA = hz + 1024; float2* bB = hz + 2048;
    const int i = tid, b = bid;
    QC S; make_qc(i, lamh, S);
    {
      const float2* h02 = (const float2*)(h0 + (size_t)b * 2048);
      float2* hrow0 = (float2*)(houtp + (size_t)b * 2048);
      float2 v = h02[i]; hz[S.sfi] = v; hrow0[i] = v;
    }
    __syncthreads();
    #pragma unroll 1
    for (int t = 0; t < 1024; ++t){
      if ((t & 7) == 0){
        if (tid == 0){
          const int xk = t >> 3;
          while (__hip_atomic_load(&gcnt[xk], __ATOMIC_RELAXED, __HIP_MEMORY_SCOPE_AGENT) < 32)
            __builtin_amdgcn_s_sleep(32);
          while (__hip_atomic_load(&wcnt[xk], __ATOMIC_RELAXED, __HIP_MEMORY_SCOPE_AGENT) < 128)
            __builtin_amdgcn_s_sleep(32);
        }
        __syncthreads();
        __threadfence();   // acquire: make producer writes visible
      }
      float* orow = outp  + ((size_t)t * 16 + b) * 2048;
      float* hrow = houtp + ((size_t)(t + 1) * 16 + b) * 2048;
      float2 pr = *(const float2*)(orow + 2 * i);   // pre (circ_x + b)
      float2 gv = *(const float2*)(hrow + 2 * i);   // gate (silu)
      fftconv(hz, bA, bB, S);
      float2 y = bA[S.sfi];
      float hx = tanh_fast(y.x + pr.x);
      float hy = tanh_fast(y.y + pr.y);
      float ox = hx * gv.x, oy = hy * gv.y;
      asm volatile("" : "+v"(hx), "+v"(hy) : "v"(gv.x), "v"(gv.y));
      float2 hv = make_float2(hx, hy);
      hz[S.sfi] = hv;
      *(float2*)(hrow + 2 * i) = hv;
      *(float2*)(orow + 2 * i) = make_float2(ox, oy);
      LDSBAR();
    }
  } else if (bid < 144){
    // ---------------- circx producer: rows cblk + 128*k ----------------
    float2* hz = (float2*)smem; float2* bA = hz + 1024; float2* bB = hz + 2048;
    const int i = tid, cblk = bid - 16;
    QC S; make_qc(i, lamx, S);
    const float2 bv = ((const float2*)bias)[i];
    #pragma unroll 1
    for (int k = 0; k < 128; ++k){
      const size_t row = (size_t)cblk + ((size_t)k << 7);
      hz[S.sfi] = ((const float2*)(x + row * 2048))[i];
      LDSBAR();
      fftconv(hz, bA, bB, S);
      float2 y = bA[S.sfi];
      ((float2*)(outp + row * 2048))[i] = cadd(y, bv);
      __syncthreads();   // drain stores before flag release
      if (tid == 0){
        __threadfence();
        __hip_atomic_fetch_add(&wcnt[k], 1, __ATOMIC_RELEASE, __HIP_MEMORY_SCOPE_AGENT);
      }
    }
  } else {
    // ---------------- gemm producer: 4 independent 128x64 tiles, LDA=40 pad ----------------
    const int q = bid - 144;
    const int g = tid >> 8, tid8 = tid & 255;
    const int tau = q * 4 + g;
    const int m0 = (tau >> 5) * 128, n0 = (tau & 31) * 64;
    unsigned short* As = (unsigned short*)(smem + g * 15360);   // 128 x 40 (padded)
    unsigned short* Bs = As + 5120;                             // 64 x 40  (padded)
    const int lane = tid8 & 63, wave = tid8 >> 6;
    const int srA = tid8 >> 1, scA = (tid8 & 1) << 4;
    const int srB = tid8 >> 2, scB = (tid8 & 3) << 3;
    const unsigned short* ga = xb + (size_t)(m0 + srA) * 2048 + scA;
    const unsigned short* gb = Wb + (size_t)(n0 + srB) * 2048 + scB;
    unsigned short* la = As + srA * 40 + scA;
    unsigned short* lb = Bs + srB * 40 + scB;
    f32x4 acc[2][4];
    #pragma unroll
    for (int m = 0; m < 2; ++m)
      #pragma unroll
      for (int n = 0; n < 4; ++n)
        acc[m][n] = f32x4{0.f, 0.f, 0.f, 0.f};
    const int arow = wave * 32 + (lane & 15);
    const int brow = lane & 15;
    const int koff = (lane >> 4) * 8;
    for (int ks = 0; ks < 64; ++ks){
      const int k0 = ks * 32;
      us8 va0 = *(const us8*)(ga + k0);
      us8 va1 = *(const us8*)(ga + k0 + 8);
      us8 vb0 = *(const us8*)(gb + k0);
      __syncthreads();
      *(us8*)(la)     = va0; *(us8*)(la + 8) = va1;
      *(us8*)(lb)     = vb0;
      __syncthreads();
      bf16x8 av[2], bvv[4];
      #pragma unroll
      for (int m = 0; m < 2; ++m) av[m] = *(const bf16x8*)(As + (arow + m * 16) * 40 + koff);
      #pragma unroll
      for (int n = 0; n < 4; ++n) bvv[n] = *(const bf16x8*)(Bs + (brow + n * 16) * 40 + koff);
      #pragma unroll
      for (int m = 0; m < 2; ++m)
        #pragma unroll
        for (int n = 0; n < 4; ++n)
          acc[m][n] = __builtin_amdgcn_mfma_f32_16x16x32_bf16(av[m], bvv[n], acc[m][n], 0, 0, 0);
    }
    #pragma unroll
    for (int n = 0; n < 4; ++n){
      const int ng = n0 + n * 16 + (lane & 15);
      const float bgv = bg[ng];
      #pragma unroll
      for (int m = 0; m < 2; ++m){
        const int mbase = m0 + wave * 32 + m * 16 + (lane >> 4) * 4;
        #pragma unroll
        for (int r = 0; r < 4; ++r){
          float v = acc[m][n][r] + bgv;
          float s = v / (1.0f + __expf(-v));
          houtp[(size_t)(mbase + r + 16) * 2048 + ng] = s;   // gate row m -> h row m+16
        }
      }
    }
    __syncthreads();
    if (tid == 0){
      __threadfence();
      __hip_atomic_fetch_add(&gcnt[q >> 3], 4, __ATOMIC_RELEASE, __HIP_MEMORY_SCOPE_AGENT);
    }
  }
}

extern "C" void kernel_launch(void* const* d_in, const int* in_sizes, int n_in,
                              void* d_out, int out_size, void* d_ws, size_t ws_size,
                              hipStream_t stream){
  const float* x  = (const float*)d_in[0];
  const float* h0 = (const float*)d_in[1];
  const float* ch = (const float*)d_in[2];
  const float* cx = (const float*)d_in[3];
  const float* Wg = (const float*)d_in[4];
  const float* bb = (const float*)d_in[5];
  const float* bg = (const float*)d_in[6];
  float* outp  = (float*)d_out;                        // [T,B,D]
  float* houtp = outp + (size_t)1024 * 16 * 2048;      // [T+1,B,D]

  char* w = (char*)d_ws;
  unsigned short* xb = (unsigned short*)w; w += (size_t)16384 * 2048 * 2;
  unsigned short* Wb = (unsigned short*)w; w += (size_t)2048 * 2048 * 2;
  float2* lamh = (float2*)w; w += 2048 * sizeof(float2);
  float2* lamx = (float2*)w; w += 2048 * sizeof(float2);
  int* flags   = (int*)w;   w += 256 * sizeof(int);

  cvt_bf16 <<<dim3(16384), dim3(256), 0, stream>>>(x,  xb, 16384 * 2048 / 8);
  cvt_bf16 <<<dim3(2048),  dim3(256), 0, stream>>>(Wg, Wb,  2048 * 2048 / 8);
  dft_c    <<<dim3(8),     dim3(256), 0, stream>>>(ch, lamh);
  dft_c    <<<dim3(8),     dim3(256), 0, stream>>>(cx, lamx);
  hipMemsetAsync(flags, 0, 256 * sizeof(int), stream);
  mega     <<<dim3(1168),  dim3(1024), 0, stream>>>(x, xb, Wb, h0, lamh, lamx,
                                                    bb, bg, outp, houtp, flags);
}

// Round 8
// 2365.240 us; speedup vs baseline: 1.7221x; 1.7166x over previous
//
#include <hip/hip_runtime.h>
#include <hip/hip_bf16.h>

// CirculantElmanCell: T=1024, B=16, D=2048
// out0: output [T,B,D] f32 ; out1: h [T+1,B,D] f32 (concatenated in d_out)

typedef __attribute__((ext_vector_type(8))) unsigned short us8;
typedef __attribute__((ext_vector_type(8))) __bf16 bf16x8;
typedef __attribute__((ext_vector_type(4))) float f32x4;

__device__ __forceinline__ int SIGF(int a){ return a ^ (((a >> 8) & 3) << 2) ^ ((a >> 6) & 3); }
__device__ __forceinline__ int rev2i(int v){ return ((v & 1) << 1) | ((v >> 1) & 1); }
__device__ __forceinline__ int PERMF(int i){
  return rev2i((i >> 8) & 3) | (rev2i((i >> 6) & 3) << 2) | (rev2i((i >> 4) & 3) << 4)
       | (rev2i((i >> 2) & 3) << 6) | (rev2i(i & 3) << 8);
}

// LDS-only barrier: no vmcnt drain (global loads/stores stay in flight)
#define LDSBAR() do { \
  asm volatile("s_waitcnt lgkmcnt(0)\n\ts_barrier" ::: "memory"); \
  __builtin_amdgcn_sched_barrier(0); \
} while (0)

__device__ __forceinline__ unsigned short f2bf(float f){
  unsigned int u = __float_as_uint(f);
  return (unsigned short)((u + 0x7FFFu + ((u >> 16) & 1u)) >> 16);
}

__device__ __forceinline__ void sincos2pi(float fr, float& sn, float& co){
#if __has_builtin(__builtin_amdgcn_sinf) && __has_builtin(__builtin_amdgcn_cosf)
  sn = __builtin_amdgcn_sinf(fr);   // v_sin_f32: revolutions
  co = __builtin_amdgcn_cosf(fr);
#else
  __sincosf(fr * 6.28318530717958647692f, &sn, &co);
#endif
}

__device__ __forceinline__ float2 cmul(float2 a, float2 b){
  return make_float2(a.x*b.x - a.y*b.y, a.x*b.y + a.y*b.x);
}
__device__ __forceinline__ float2 cmulc(float2 a, float2 b){   // a * conj(b)
  return make_float2(a.x*b.x + a.y*b.y, a.y*b.x - a.x*b.y);
}
__device__ __forceinline__ float2 cadd(float2 a, float2 b){ return make_float2(a.x+b.x, a.y+b.y); }
__device__ __forceinline__ float2 csub(float2 a, float2 b){ return make_float2(a.x-b.x, a.y-b.y); }

__device__ __forceinline__ float tanh_fast(float x){
  float e = __expf(2.0f * x);
  return 1.0f - 2.0f / (e + 1.0f);
}

__device__ __forceinline__ float2 wn(int num, float dinv, int sgn){
  float sn, co; sincos2pi((float)num * dinv, sn, co);
  return make_float2(co, sgn > 0 ? sn : -sn);
}

// ---------------- cross-lane exchange primitives ----------------
template<int CTRL>
__device__ __forceinline__ float2 dpp2(float2 v){
  float2 r;
  r.x = __int_as_float(__builtin_amdgcn_mov_dpp(__float_as_int(v.x), CTRL, 0xF, 0xF, true));
  r.y = __int_as_float(__builtin_amdgcn_mov_dpp(__float_as_int(v.y), CTRL, 0xF, 0xF, true));
  return r;
}
template<int IMM>
__device__ __forceinline__ float2 swz2(float2 v){
  float2 r;
  r.x = __int_as_float(__builtin_amdgcn_ds_swizzle(__float_as_int(v.x), IMM));
  r.y = __int_as_float(__builtin_amdgcn_ds_swizzle(__float_as_int(v.y), IMM));
  return r;
}
__device__ __forceinline__ float2 bperm2(int addr, float2 v){
  float2 r;
  r.x = __int_as_float(__builtin_amdgcn_ds_bpermute(addr, __float_as_int(v.x)));
  r.y = __int_as_float(__builtin_amdgcn_ds_bpermute(addr, __float_as_int(v.y)));
  return r;
}
#define DPP_XOR1 0xB1  // quad_perm [1,0,3,2]
#define DPP_XOR2 0x4E  // quad_perm [2,3,0,1]

// ---------------- radix-4 building blocks (verbatim, verified R5-R7) ----------------
template<int POS>  // POS=0: fwd, POS=1: inv (twiddle conjugated)
__device__ __forceinline__ float2 lds4(const float2* buf, int a0, int a1, int a2, int a3,
                                       float sB, float sD, bool sel, float2 tw){
  float2 in0 = buf[a0], in1 = buf[a1], in2 = buf[a2], in3 = buf[a3];
  float2 u = make_float2(fmaf(sB, in2.x, in0.x), fmaf(sB, in2.y, in0.y));
  float2 v = make_float2(fmaf(sB, in3.x, in1.x), fmaf(sB, in3.y, in1.y));
  float2 iv = POS ? make_float2(-v.y, v.x) : make_float2(v.y, -v.x);
  float2 se = sel ? iv : v;
  float2 X = make_float2(fmaf(sD, se.x, u.x), fmaf(sD, se.y, u.y));
  return POS ? cmulc(X, tw) : cmul(X, tw);
}

template<int POS>
__device__ __forceinline__ float2 round2f(float2 own, float2 par, bool c0, bool c1, float sgn0){
  float2 vk = c0 ? par : own;
  float2 vr = c0 ? own : par;
  float2 vrr = POS ? make_float2(-vr.y, vr.x) : make_float2(vr.y, -vr.x);
  float2 rot = c1 ? vrr : vr;
  return make_float2(fmaf(sgn0, rot.x, vk.x), fmaf(sgn0, rot.y, vk.y));
}

template<int POS>
__device__ __forceinline__ float2 lanes3(float2 T, int bpa,
    float sH2, bool c02, bool c12, float sL2, float2 tw2,
    float sH3, bool c03, bool c13, float sL3, float2 tw3,
    float sH4, bool c04, bool c14, float sL4){
  { // d=16: lane^32 (bpermute), lane^16 (swizzle)
    float2 par = bperm2(bpa, T);
    T.x = fmaf(sH2, T.x, par.x); T.y = fmaf(sH2, T.y, par.y);
    float2 p2 = swz2<0x401F>(T);
    T = round2f<POS>(T, p2, c02, c12, sL2);
    T = POS ? cmulc(T, tw2) : cmul(T, tw2);
  }
  { // d=4: lane^8, lane^4
    float2 par = swz2<0x201F>(T);
    T.x = fmaf(sH3, T.x, par.x); T.y = fmaf(sH3, T.y, par.y);
    float2 p2 = swz2<0x101F>(T);
    T = round2f<POS>(T, p2, c03, c13, sL3);
    T = POS ? cmulc(T, tw3) : cmul(T, tw3);
  }
  { // d=1: lane^2, lane^1
    float2 par = dpp2<DPP_XOR2>(T);
    T.x = fmaf(sH4, T.x, par.x); T.y = fmaf(sH4, T.y, par.y);
    float2 p2 = dpp2<DPP_XOR1>(T);
    T = round2f<POS>(T, p2, c04, c14, sL4);
  }
  return T;
}

// ---------------- per-thread constants ----------------
struct QC {
  float2 tw0, tw1, tw2, tw3, P, Q;
  float sB0, sD0, sB1, sD1;
  float sH2, sL2, sH3, sL3, sH4, sL4;
  bool sel0, sel1, c02, c12, c03, c13, c04, c14;
  int sfi, swP, smir, bpa;
  int aA0, aA1, aA2, aA3, aB0, aB1, aB2, aB3;
};

__device__ __forceinline__ void make_qc(int i, const float2* __restrict__ lam_g, QC& S){
  const int p0 = rev2i((i >> 8) & 3);
  const int p1 = rev2i((i >> 6) & 3);
  const int p2v = rev2i((i >> 4) & 3);
  const int p3v = rev2i((i >> 2) & 3);
  S.tw0 = wn(((i & 255) * p0) & 1023, 1.0f/1024.0f, -1);
  S.tw1 = wn(((i & 63) * p1) & 255, 1.0f/256.0f, -1);
  S.tw2 = wn(((i & 15) * p2v) & 63, 1.0f/64.0f, -1);
  S.tw3 = wn(((i & 3) * p3v) & 15, 1.0f/16.0f, -1);
  // mid-stage fold: out = P*zk + Q*conj(zp)
  float2 w = wn(i & 2047, 1.0f/2048.0f, -1);
  float2 lamA = lam_g[i], lamB = lam_g[i + 1024];
  float2 al = make_float2(0.5f*(1.0f + w.y), -0.5f*w.x);   // (1 - i w)/2
  float2 be = make_float2(0.5f*(1.0f - w.y),  0.5f*w.x);   // (1 + i w)/2
  float2 ga = make_float2(1.0f + w.y,  w.x);               // 1 + i conj(w)
  float2 de = make_float2(1.0f - w.y, -w.x);               // 1 - i conj(w)
  float2 gA = cmul(ga, lamA), dB = cmul(de, lamB);
  S.P = cadd(cmul(gA, al), cmul(dB, be));
  S.Q = cadd(cmul(gA, be), cmul(dB, al));
  S.sB0 = (p0 & 1) ? -1.f : 1.f; S.sD0 = (p0 & 2) ? -1.f : 1.f; S.sel0 = p0 & 1;
  S.sB1 = (p1 & 1) ? -1.f : 1.f; S.sD1 = (p1 & 2) ? -1.f : 1.f; S.sel1 = p1 & 1;
  S.c02 = (i >> 4) & 1; S.c12 = (i >> 5) & 1;
  S.c03 = (i >> 2) & 1; S.c13 = (i >> 3) & 1;
  S.c04 = i & 1;        S.c14 = (i >> 1) & 1;
  S.sH2 = S.c12 ? -1.f : 1.f; S.sL2 = S.c02 ? -1.f : 1.f;
  S.sH3 = S.c13 ? -1.f : 1.f; S.sL3 = S.c03 ? -1.f : 1.f;
  S.sH4 = S.c14 ? -1.f : 1.f; S.sL4 = S.c04 ? -1.f : 1.f;
  S.sfi = SIGF(i); S.swP = SIGF(PERMF(i)); S.smir = SIGF((1024 - i) & 1023);
  S.bpa = ((i & 63) ^ 32) << 2;
  const int r256 = i & 255;
  S.aA0 = SIGF(r256); S.aA1 = SIGF(r256 + 256); S.aA2 = SIGF(r256 + 512); S.aA3 = SIGF(r256 + 768);
  const int b64 = (i & ~255) + (i & 63);
  S.aB0 = SIGF(b64); S.aB1 = SIGF(b64 + 64); S.aB2 = SIGF(b64 + 128); S.aB3 = SIGF(b64 + 192);
}

// full conv body: fwd FFT, spectral multiply, inv FFT; result at bA[S.sfi]
__device__ __forceinline__ void fftconv(float2* hz, float2* bA, float2* bB, const QC& S){
  float2 T = lds4<0>(hz, S.aA0, S.aA1, S.aA2, S.aA3, S.sB0, S.sD0, S.sel0, S.tw0);
  bA[S.sfi] = T; LDSBAR();
  T = lds4<0>(bA, S.aB0, S.aB1, S.aB2, S.aB3, S.sB1, S.sD1, S.sel1, S.tw1);
  T = lanes3<0>(T, S.bpa, S.sH2, S.c02, S.c12, S.sL2, S.tw2,
                S.sH3, S.c03, S.c13, S.sL3, S.tw3, S.sH4, S.c04, S.c14, S.sL4);
  bB[S.swP] = T; LDSBAR();
  {
    float2 zk = bB[S.sfi], zp = bB[S.smir];
    bA[S.sfi] = cadd(cmul(S.P, zk), cmulc(S.Q, zp));
  }
  LDSBAR();
  T = lds4<1>(bA, S.aA0, S.aA1, S.aA2, S.aA3, S.sB0, S.sD0, S.sel0, S.tw0);
  bB[S.sfi] = T; LDSBAR();
  T = lds4<1>(bB, S.aB0, S.aB1, S.aB2, S.aB3, S.sB1, S.sD1, S.sel1, S.tw1);
  T = lanes3<1>(T, S.bpa, S.sH2, S.c02, S.c12, S.sL2, S.tw2,
                S.sH3, S.c03, S.c13, S.sL3, S.tw3, S.sH4, S.c04, S.c14, S.sL4);
  bA[S.swP] = T; LDSBAR();
}

// ---------------- f32 -> bf16 bulk convert ----------------
__global__ __launch_bounds__(256) void cvt_bf16(const float* __restrict__ in,
                                                unsigned short* __restrict__ out, int n8){
  int i = blockIdx.x * 256 + threadIdx.x;
  if (i >= n8) return;
  float4 a = ((const float4*)in)[2 * i];
  float4 b = ((const float4*)in)[2 * i + 1];
  us8 r;
  r[0] = f2bf(a.x); r[1] = f2bf(a.y); r[2] = f2bf(a.z); r[3] = f2bf(a.w);
  r[4] = f2bf(b.x); r[5] = f2bf(b.y); r[6] = f2bf(b.z); r[7] = f2bf(b.w);
  ((us8*)out)[i] = r;
}

// ---------------- lam[k] = fft(c)[k] / 2048 ----------------
__global__ __launch_bounds__(256) void dft_c(const float* __restrict__ c, float2* __restrict__ lam){
  __shared__ float cs[2048];
  int tid = threadIdx.x;
  for (int i = tid; i < 2048; i += 256) cs[i] = c[i];
  __syncthreads();
  int k = blockIdx.x * 256 + tid;
  float sr = 0.f, si = 0.f;
  for (int j = 0; j < 2048; ++j){
    int ph = (j * k) & 2047;
    float sn, co; sincos2pi((float)ph * (1.0f / 2048.0f), sn, co);
    float cv = cs[j];
    sr = __fmaf_rn(cv,  co, sr);
    si = __fmaf_rn(-cv, sn, si);
  }
  lam[k] = make_float2(sr * (1.0f / 2048.0f), si * (1.0f / 2048.0f));
}

// =====================================================================
// mega v3: FENCE-FREE producer->consumer protocol.
// Producers write pre/gate with SYSTEM-scope (sc0 sc1, L2-bypass) stores;
// __syncthreads()'s vmcnt(0) drain guarantees L3 visibility; flag = relaxed
// system-scope fetch_add. Consumer polls flags (relaxed system) and reads
// pre/gate with SYSTEM-scope loads. Zero cache-maintenance ops.
// 96KB static LDS -> 1 block/CU (recur CUs stay isolated).
// blocks [0,16) recur ; [16,144) circx producers ; [144,1168) gemm.
// =====================================================================
__global__ __launch_bounds__(1024, 4) void mega(
    const float* __restrict__ x, const unsigned short* __restrict__ xb,
    const unsigned short* __restrict__ Wb, const float* __restrict__ h0,
    const float2* __restrict__ lamh, const float2* __restrict__ lamx,
    const float* __restrict__ bias, const float* __restrict__ bg,
    float* __restrict__ outp, float* __restrict__ houtp, int* __restrict__ flags){
  __shared__ __align__(16) char smem[98304];   // 96KB: forces 1 block/CU
  const int bid = blockIdx.x;
  const int tid = threadIdx.x;
  int* gcnt = flags;
  int* wcnt = flags + 128;

  if (bid < 16){
    // ---------------- recur consumer (dedicated CU) ----------------
    float2* hz = (float2*)smem; float2* bA = hz + 1024; float2* bB = hz + 2048;
    const int i = tid, b = bid;
    QC S; make_qc(i, lamh, S);
    {
      const float2* h02 = (const float2*)(h0 + (size_t)b * 2048);
      float2* hrow0 = (float2*)(houtp + (size_t)b * 2048);
      float2 v = h02[i]; hz[S.sfi] = v; hrow0[i] = v;
    }
    __syncthreads();
    #pragma unroll 1
    for (int t = 0; t < 1024; ++t){
      if ((t & 7) == 0){
        if (tid == 0){
          const int xk = t >> 3;
          while (__hip_atomic_load(&gcnt[xk], __ATOMIC_RELAXED, __HIP_MEMORY_SCOPE_SYSTEM) < 32)
            __builtin_amdgcn_s_sleep(16);
          while (__hip_atomic_load(&wcnt[xk], __ATOMIC_RELAXED, __HIP_MEMORY_SCOPE_SYSTEM) < 128)
            __builtin_amdgcn_s_sleep(16);
        }
        __syncthreads();
      }
      float* orow = outp  + ((size_t)t * 16 + b) * 2048;
      float* hrow = houtp + ((size_t)(t + 1) * 16 + b) * 2048;
      // system-scope (L2-bypass) loads: read producer data straight from L3
      float2 pr, gv;
      pr.x = __hip_atomic_load(orow + 2*i,     __ATOMIC_RELAXED, __HIP_MEMORY_SCOPE_SYSTEM);
      pr.y = __hip_atomic_load(orow + 2*i + 1, __ATOMIC_RELAXED, __HIP_MEMORY_SCOPE_SYSTEM);
      gv.x = __hip_atomic_load(hrow + 2*i,     __ATOMIC_RELAXED, __HIP_MEMORY_SCOPE_SYSTEM);
      gv.y = __hip_atomic_load(hrow + 2*i + 1, __ATOMIC_RELAXED, __HIP_MEMORY_SCOPE_SYSTEM);
      fftconv(hz, bA, bB, S);
      float2 y = bA[S.sfi];
      float hx = tanh_fast(y.x + pr.x);
      float hy = tanh_fast(y.y + pr.y);
      float ox = hx * gv.x, oy = hy * gv.y;
      asm volatile("" : "+v"(hx), "+v"(hy) : "v"(gv.x), "v"(gv.y));
      float2 hv = make_float2(hx, hy);
      hz[S.sfi] = hv;
      *(float2*)(hrow + 2 * i) = hv;
      *(float2*)(orow + 2 * i) = make_float2(ox, oy);
      LDSBAR();
    }
  } else if (bid < 144){
    // ---------------- circx producer: rows cblk + 128*k ----------------
    float2* hz = (float2*)smem; float2* bA = hz + 1024; float2* bB = hz + 2048;
    const int i = tid, cblk = bid - 16;
    QC S; make_qc(i, lamx, S);
    const float2 bv = ((const float2*)bias)[i];
    #pragma unroll 1
    for (int k = 0; k < 128; ++k){
      const size_t row = (size_t)cblk + ((size_t)k << 7);
      hz[S.sfi] = ((const float2*)(x + row * 2048))[i];
      LDSBAR();
      fftconv(hz, bA, bB, S);
      float2 y = bA[S.sfi];
      float* pd = outp + row * 2048 + 2 * i;
      __hip_atomic_store(pd,     y.x + bv.x, __ATOMIC_RELAXED, __HIP_MEMORY_SCOPE_SYSTEM);
      __hip_atomic_store(pd + 1, y.y + bv.y, __ATOMIC_RELAXED, __HIP_MEMORY_SCOPE_SYSTEM);
      __syncthreads();   // vmcnt(0) drain: stores complete at L3 before flag
      if (tid == 0)
        __hip_atomic_fetch_add(&wcnt[k], 1, __ATOMIC_RELAXED, __HIP_MEMORY_SCOPE_SYSTEM);
    }
  } else {
    // ---------------- gemm producer: 4 independent 128x64 tiles, LDA=40 pad ----------------
    const int q = bid - 144;
    const int g = tid >> 8, tid8 = tid & 255;
    const int tau = q * 4 + g;
    const int m0 = (tau >> 5) * 128, n0 = (tau & 31) * 64;
    unsigned short* As = (unsigned short*)(smem + g * 15360);   // 128 x 40 (padded)
    unsigned short* Bs = As + 5120;                             // 64 x 40  (padded)
    const int lane = tid8 & 63, wave = tid8 >> 6;
    const int srA = tid8 >> 1, scA = (tid8 & 1) << 4;
    const int srB = tid8 >> 2, scB = (tid8 & 3) << 3;
    const unsigned short* ga = xb + (size_t)(m0 + srA) * 2048 + scA;
    const unsigned short* gb = Wb + (size_t)(n0 + srB) * 2048 + scB;
    unsigned short* la = As + srA * 40 + scA;
    unsigned short* lb = Bs + srB * 40 + scB;
    f32x4 acc[2][4];
    #pragma unroll
    for (int m = 0; m < 2; ++m)
      #pragma unroll
      for (int n = 0; n < 4; ++n)
        acc[m][n] = f32x4{0.f, 0.f, 0.f, 0.f};
    const int arow = wave * 32 + (lane & 15);
    const int brow = lane & 15;
    const int koff = (lane >> 4) * 8;
    for (int ks = 0; ks < 64; ++ks){
      const int k0 = ks * 32;
      us8 va0 = *(const us8*)(ga + k0);
      us8 va1 = *(const us8*)(ga + k0 + 8);
      us8 vb0 = *(const us8*)(gb + k0);
      __syncthreads();
      *(us8*)(la)     = va0; *(us8*)(la + 8) = va1;
      *(us8*)(lb)     = vb0;
      __syncthreads();
      bf16x8 av[2], bvv[4];
      #pragma unroll
      for (int m = 0; m < 2; ++m) av[m] = *(const bf16x8*)(As + (arow + m * 16) * 40 + koff);
      #pragma unroll
      for (int n = 0; n < 4; ++n) bvv[n] = *(const bf16x8*)(Bs + (brow + n * 16) * 40 + koff);
      #pragma unroll
      for (int m = 0; m < 2; ++m)
        #pragma unroll
        for (int n = 0; n < 4; ++n)
          acc[m][n] = __builtin_amdgcn_mfma_f32_16x16x32_bf16(av[m], bvv[n], acc[m][n], 0, 0, 0);
    }
    #pragma unroll
    for (int n = 0; n < 4; ++n){
      const int ng = n0 + n * 16 + (lane & 15);
      const float bgv = bg[ng];
      #pragma unroll
      for (int m = 0; m < 2; ++m){
        const int mbase = m0 + wave * 32 + m * 16 + (lane >> 4) * 4;
        #pragma unroll
        for (int r = 0; r < 4; ++r){
          float v = acc[m][n][r] + bgv;
          float s = v / (1.0f + __expf(-v));
          __hip_atomic_store(&houtp[(size_t)(mbase + r + 16) * 2048 + ng], s,
                             __ATOMIC_RELAXED, __HIP_MEMORY_SCOPE_SYSTEM);
        }
      }
    }
    __syncthreads();   // vmcnt(0) drain: stores complete at L3 before flag
    if (tid == 0)
      __hip_atomic_fetch_add(&gcnt[q >> 3], 4, __ATOMIC_RELAXED, __HIP_MEMORY_SCOPE_SYSTEM);
  }
}

extern "C" void kernel_launch(void* const* d_in, const int* in_sizes, int n_in,
                              void* d_out, int out_size, void* d_ws, size_t ws_size,
                              hipStream_t stream){
  const float* x  = (const float*)d_in[0];
  const float* h0 = (const float*)d_in[1];
  const float* ch = (const float*)d_in[2];
  const float* cx = (const float*)d_in[3];
  const float* Wg = (const float*)d_in[4];
  const float* bb = (const float*)d_in[5];
  const float* bg = (const float*)d_in[6];
  float* outp  = (float*)d_out;                        // [T,B,D]
  float* houtp = outp + (size_t)1024 * 16 * 2048;      // [T+1,B,D]

  char* w = (char*)d_ws;
  unsigned short* xb = (unsigned short*)w; w += (size_t)16384 * 2048 * 2;
  unsigned short* Wb = (unsigned short*)w; w += (size_t)2048 * 2048 * 2;
  float2* lamh = (float2*)w; w += 2048 * sizeof(float2);
  float2* lamx = (float2*)w; w += 2048 * sizeof(float2);
  int* flags   = (int*)w;   w += 256 * sizeof(int);

  cvt_bf16 <<<dim3(16384), dim3(256), 0, stream>>>(x,  xb, 16384 * 2048 / 8);
  cvt_bf16 <<<dim3(2048),  dim3(256), 0, stream>>>(Wg, Wb,  2048 * 2048 / 8);
  dft_c    <<<dim3(8),     dim3(256), 0, stream>>>(ch, lamh);
  dft_c    <<<dim3(8),     dim3(256), 0, stream>>>(cx, lamx);
  hipMemsetAsync(flags, 0, 256 * sizeof(int), stream);
  mega     <<<dim3(1168),  dim3(1024), 0, stream>>>(x, xb, Wb, h0, lamh, lamx,
                                                    bb, bg, outp, houtp, flags);
}